// Round 1
// baseline (471.015 us; speedup 1.0000x reference)
//
#include <hip/hip_runtime.h>
#include <hip/hip_cooperative_groups.h>
#include <math.h>

namespace cg = cooperative_groups;

#define C_DIM 96
#define CR 24
#define H_DIM 128
#define W_DIM 128
#define B_DIM 32
#define CHUNKS 4
#define ROWS_PER_CHUNK (H_DIM / CHUNKS)
#define N_PLANES (B_DIM * C_DIM)      // 3072
#define N_PAIRS  (N_PLANES / 2)       // 1536
#define NBLK 768                      // 3 blocks/CU target for cooperative residency

typedef float nfloat4 __attribute__((ext_vector_type(4)));   // native vec for nontemporal builtin

// ---------------------------------------------------------------------------
// Merged cooperative kernel: phase 1 pools the SAME plane-pairs this block
// will later convolve (L2 locality on the re-read), grid.sync(), phase 2
// runs the dynamic-weight MLP + depthwise conv. Phase 2 iterates pairs in
// REVERSE so the most-recently-pooled (cache-hot) pair is convolved first.
// ---------------------------------------------------------------------------
__global__ void __launch_bounds__(256) merged_kernel(const float* __restrict__ x,
                                                     float* __restrict__ pooled,
                                                     const float* __restrict__ w1,
                                                     const float* __restrict__ gamma,
                                                     const float* __restrict__ beta,
                                                     const float* __restrict__ rmean,
                                                     const float* __restrict__ rvar,
                                                     const float* __restrict__ w2,
                                                     const float* __restrict__ b2,
                                                     const float* __restrict__ bias,
                                                     float* __restrict__ out) {
    const int tid = threadIdx.x;
    const int nb = gridDim.x;
    const int kmax = (N_PAIRS - 1 - (int)blockIdx.x) / nb;

    __shared__ float ls[4];
    __shared__ float pl[C_DIM];
    __shared__ float h1[CR];
    __shared__ float wsm[2][10];            // 9 taps + bias per plane

    // ---------------- Phase 1: adaptive avg pool ----------------
    for (int k = 0; k <= kmax; ++k) {
        int pair = blockIdx.x + k * nb;
        #pragma unroll
        for (int pp = 0; pp < 2; ++pp) {
            int plane = pair * 2 + pp;
            const float4* xp = (const float4*)(x + (size_t)plane * (H_DIM * W_DIM));
            float s = 0.f;
            for (int i = tid; i < 4096; i += 256) {
                float4 v = xp[i];
                s += v.x + v.y + v.z + v.w;
            }
            for (int off = 32; off; off >>= 1) s += __shfl_down(s, off, 64);
            if ((tid & 63) == 0) ls[tid >> 6] = s;
            __syncthreads();
            if (tid == 0) pooled[plane] = (ls[0] + ls[1] + ls[2] + ls[3]) * (1.f / (H_DIM * W_DIM));
            __syncthreads();
        }
    }

    cg::this_grid().sync();

    // ---------------- Phase 2: MLP + per-sample depthwise 3x3 ----------------
    for (int k = kmax; k >= 0; --k) {
        int pair = blockIdx.x + k * nb;
        int plane0 = pair * 2;              // even plane index
        int b = plane0 / C_DIM;
        int c0 = plane0 % C_DIM;            // channel of plane0; plane1 is c0+1

        if (tid < C_DIM) pl[tid] = pooled[b * C_DIM + tid];
        __syncthreads();
        if (tid < CR) {
            float s = 0.f;
            const float* wr = w1 + tid * C_DIM;
            #pragma unroll 8
            for (int c = 0; c < C_DIM; c++) s += pl[c] * wr[c];
            s = (s - rmean[tid]) * rsqrtf(rvar[tid] + 1e-5f) * gamma[tid] + beta[tid];
            h1[tid] = 1.f / (1.f + expf(-s));
        }
        __syncthreads();
        if (tid < 20) {
            if (tid < 18) {
                int p = tid / 9, kk = tid % 9;
                int row = (c0 + p) * 9 + kk;     // wdyn flat index within batch
                float s = b2[row];
                const float* wr = w2 + row * CR;
                #pragma unroll
                for (int j = 0; j < CR; j++) s += h1[j] * wr[j];
                wsm[p][kk] = s;
            } else {
                wsm[tid - 18][9] = bias[c0 + (tid - 18)];
            }
        }
        __syncthreads();

        int g = tid & 31;
        int chunk = (tid >> 5) & 3;
        int p = tid >> 7;
        int plane = plane0 + p;
        int col = g << 2;
        int r0 = chunk * ROWS_PER_CHUNK;

        const float* xp = x + (size_t)plane * (H_DIM * W_DIM);
        float* op = out + (size_t)plane * (H_DIM * W_DIM);
        const float* wv = wsm[p];
        float w00 = wv[0], w01 = wv[1], w02 = wv[2];
        float w10 = wv[3], w11 = wv[4], w12 = wv[5];
        float w20 = wv[6], w21 = wv[7], w22 = wv[8];
        float bb = wv[9];
        const bool leftEdge = (g == 0), rightEdge = (g == 31);

        float4 pv, cv, nv;
        float plh, prh, clh, crh, nlh, nrh;

        {
            int r = r0 - 1;
            float4 v;
            if (r >= 0) v = *(const float4*)(xp + r * W_DIM + col);
            else { v.x = v.y = v.z = v.w = 0.f; }
            float l = __shfl_up(v.w, 1, 64);
            float rr = __shfl_down(v.x, 1, 64);
            pv = v; plh = leftEdge ? 0.f : l; prh = rightEdge ? 0.f : rr;
        }
        {
            float4 v = *(const float4*)(xp + r0 * W_DIM + col);
            float l = __shfl_up(v.w, 1, 64);
            float rr = __shfl_down(v.x, 1, 64);
            cv = v; clh = leftEdge ? 0.f : l; crh = rightEdge ? 0.f : rr;
        }

        #pragma unroll 4
        for (int i = 0; i < ROWS_PER_CHUNK; i++) {
            int r = r0 + i;
            float4 v;
            if (r + 1 < H_DIM) v = *(const float4*)(xp + (r + 1) * W_DIM + col);
            else { v.x = v.y = v.z = v.w = 0.f; }
            float l = __shfl_up(v.w, 1, 64);
            float rr = __shfl_down(v.x, 1, 64);
            nv = v; nlh = leftEdge ? 0.f : l; nrh = rightEdge ? 0.f : rr;

            nfloat4 o;
            o.x = w00 * plh  + w01 * pv.x + w02 * pv.y
                + w10 * clh  + w11 * cv.x + w12 * cv.y
                + w20 * nlh  + w21 * nv.x + w22 * nv.y + bb;
            o.y = w00 * pv.x + w01 * pv.y + w02 * pv.z
                + w10 * cv.x + w11 * cv.y + w12 * cv.z
                + w20 * nv.x + w21 * nv.y + w22 * nv.z + bb;
            o.z = w00 * pv.y + w01 * pv.z + w02 * pv.w
                + w10 * cv.y + w11 * cv.z + w12 * cv.w
                + w20 * nv.y + w21 * nv.z + w22 * nv.w + bb;
            o.w = w00 * pv.z + w01 * pv.w + w02 * prh
                + w10 * cv.z + w11 * cv.w + w12 * crh
                + w20 * nv.z + w21 * nv.w + w22 * nrh + bb;
            __builtin_nontemporal_store(o, (nfloat4*)(op + r * W_DIM + col));

            pv = cv; plh = clh; prh = crh;
            cv = nv; clh = nlh; crh = nrh;
        }
        __syncthreads();   // protect shared reuse across pairs
    }
}

// ---------------------------------------------------------------------------
// Fallback path (verified previous-best two-kernel version) in case the
// cooperative launch is rejected under graph capture / residency limits.
// ---------------------------------------------------------------------------
__global__ void pool_kernel(const float* __restrict__ x, float* __restrict__ pooled) {
    int plane = blockIdx.x;                       // b*96 + c, 3072 planes
    const float4* xp = (const float4*)(x + (size_t)plane * (H_DIM * W_DIM));
    float s = 0.f;
    for (int i = threadIdx.x; i < 4096; i += 256) {
        float4 v = xp[i];
        s += v.x + v.y + v.z + v.w;
    }
    for (int off = 32; off; off >>= 1) s += __shfl_down(s, off, 64);
    __shared__ float ls[4];
    int lane = threadIdx.x & 63, wv = threadIdx.x >> 6;
    if (lane == 0) ls[wv] = s;
    __syncthreads();
    if (threadIdx.x == 0) {
        float t = ls[0] + ls[1] + ls[2] + ls[3];
        pooled[plane] = t * (1.f / (H_DIM * W_DIM));
    }
}

__global__ void __launch_bounds__(256) fused_dwconv_kernel(const float* __restrict__ x,
                                                           const float* __restrict__ pooled,
                                                           const float* __restrict__ w1,
                                                           const float* __restrict__ gamma,
                                                           const float* __restrict__ beta,
                                                           const float* __restrict__ rmean,
                                                           const float* __restrict__ rvar,
                                                           const float* __restrict__ w2,
                                                           const float* __restrict__ b2,
                                                           const float* __restrict__ bias,
                                                           float* __restrict__ out) {
    int tid = threadIdx.x;
    int plane0 = blockIdx.x * 2;            // even plane index
    int b = plane0 / C_DIM;
    int c0 = plane0 % C_DIM;                // channel of plane0; plane1 is c0+1

    __shared__ float pl[C_DIM];
    __shared__ float h1[CR];
    __shared__ float wsm[2][10];            // 9 taps + bias per plane

    if (tid < C_DIM) pl[tid] = pooled[b * C_DIM + tid];
    __syncthreads();
    if (tid < CR) {
        float s = 0.f;
        const float* wr = w1 + tid * C_DIM;
        #pragma unroll 8
        for (int c = 0; c < C_DIM; c++) s += pl[c] * wr[c];
        s = (s - rmean[tid]) * rsqrtf(rvar[tid] + 1e-5f) * gamma[tid] + beta[tid];
        h1[tid] = 1.f / (1.f + expf(-s));
    }
    __syncthreads();
    if (tid < 20) {
        if (tid < 18) {
            int p = tid / 9, k = tid % 9;
            int row = (c0 + p) * 9 + k;     // wdyn flat index within batch
            float s = b2[row];
            const float* wr = w2 + row * CR;
            #pragma unroll
            for (int j = 0; j < CR; j++) s += h1[j] * wr[j];
            wsm[p][k] = s;
        } else {
            wsm[tid - 18][9] = bias[c0 + (tid - 18)];
        }
    }
    __syncthreads();

    int g = tid & 31;
    int chunk = (tid >> 5) & 3;
    int p = tid >> 7;
    int plane = plane0 + p;
    int col = g << 2;
    int r0 = chunk * ROWS_PER_CHUNK;

    const float* xp = x + (size_t)plane * (H_DIM * W_DIM);
    float* op = out + (size_t)plane * (H_DIM * W_DIM);
    const float* wv = wsm[p];
    float w00 = wv[0], w01 = wv[1], w02 = wv[2];
    float w10 = wv[3], w11 = wv[4], w12 = wv[5];
    float w20 = wv[6], w21 = wv[7], w22 = wv[8];
    float bb = wv[9];
    const bool leftEdge = (g == 0), rightEdge = (g == 31);

    float4 pv, cv, nv;
    float plh, prh, clh, crh, nlh, nrh;

    {
        int r = r0 - 1;
        float4 v;
        if (r >= 0) v = *(const float4*)(xp + r * W_DIM + col);
        else { v.x = v.y = v.z = v.w = 0.f; }
        float l = __shfl_up(v.w, 1, 64);
        float rr = __shfl_down(v.x, 1, 64);
        pv = v; plh = leftEdge ? 0.f : l; prh = rightEdge ? 0.f : rr;
    }
    {
        float4 v = *(const float4*)(xp + r0 * W_DIM + col);
        float l = __shfl_up(v.w, 1, 64);
        float rr = __shfl_down(v.x, 1, 64);
        cv = v; clh = leftEdge ? 0.f : l; crh = rightEdge ? 0.f : rr;
    }

    #pragma unroll 4
    for (int i = 0; i < ROWS_PER_CHUNK; i++) {
        int r = r0 + i;
        float4 v;
        if (r + 1 < H_DIM) v = *(const float4*)(xp + (r + 1) * W_DIM + col);
        else { v.x = v.y = v.z = v.w = 0.f; }
        float l = __shfl_up(v.w, 1, 64);
        float rr = __shfl_down(v.x, 1, 64);
        nv = v; nlh = leftEdge ? 0.f : l; nrh = rightEdge ? 0.f : rr;

        nfloat4 o;
        o.x = w00 * plh  + w01 * pv.x + w02 * pv.y
            + w10 * clh  + w11 * cv.x + w12 * cv.y
            + w20 * nlh  + w21 * nv.x + w22 * nv.y + bb;
        o.y = w00 * pv.x + w01 * pv.y + w02 * pv.z
            + w10 * cv.x + w11 * cv.y + w12 * cv.z
            + w20 * nv.x + w21 * nv.y + w22 * nv.z + bb;
        o.z = w00 * pv.y + w01 * pv.z + w02 * pv.w
            + w10 * cv.y + w11 * cv.z + w12 * cv.w
            + w20 * nv.y + w21 * nv.z + w22 * nv.w + bb;
        o.w = w00 * pv.z + w01 * pv.w + w02 * prh
            + w10 * cv.z + w11 * cv.w + w12 * crh
            + w20 * nv.z + w21 * nv.w + w22 * nrh + bb;
        __builtin_nontemporal_store(o, (nfloat4*)(op + r * W_DIM + col));

        pv = cv; plh = clh; prh = crh;
        cv = nv; clh = nlh; crh = nrh;
    }
}

extern "C" void kernel_launch(void* const* d_in, const int* in_sizes, int n_in,
                              void* d_out, int out_size, void* d_ws, size_t ws_size,
                              hipStream_t stream) {
    const float* x     = (const float*)d_in[0];
    const float* w1    = (const float*)d_in[1];
    const float* gamma = (const float*)d_in[2];
    const float* beta  = (const float*)d_in[3];
    const float* rmean = (const float*)d_in[4];
    const float* rvar  = (const float*)d_in[5];
    const float* w2    = (const float*)d_in[6];
    const float* b2    = (const float*)d_in[7];
    const float* bias  = (const float*)d_in[8];
    float* out = (float*)d_out;

    float* pooled = (float*)d_ws;                           // 3072 floats

    // Choose a cooperative grid that is guaranteed co-resident.
    static int nb = 0;
    if (nb == 0) {
        int mb = 0;
        hipError_t qe = hipOccupancyMaxActiveBlocksPerMultiprocessor(&mb, merged_kernel, 256, 0);
        if (qe != hipSuccess || mb <= 0) { mb = 3; (void)hipGetLastError(); }
        long cap = (long)mb * 256;                          // 256 CUs on MI355X
        nb = (int)(cap < NBLK ? cap : NBLK);
        if (nb < 1) nb = 1;
    }

    void* kargs[] = { (void*)&x, (void*)&pooled, (void*)&w1, (void*)&gamma, (void*)&beta,
                      (void*)&rmean, (void*)&rvar, (void*)&w2, (void*)&b2, (void*)&bias,
                      (void*)&out };
    hipError_t e = hipLaunchCooperativeKernel((const void*)merged_kernel,
                                              dim3(nb), dim3(256), kargs, 0, stream);
    if (e != hipSuccess) {
        (void)hipGetLastError();                            // clear, take fallback path
        pool_kernel<<<N_PLANES, 256, 0, stream>>>(x, pooled);
        fused_dwconv_kernel<<<N_PAIRS, 256, 0, stream>>>(
            x, pooled, w1, gamma, beta, rmean, rvar, w2, b2, bias, out);
    }
}

// Round 3
// 389.853 us; speedup vs baseline: 1.2082x; 1.2082x over previous
//
#include <hip/hip_runtime.h>
#include <math.h>

#define C_DIM 96
#define CR 24
#define H_DIM 128
#define W_DIM 128
#define B_DIM 32
#define CHUNKS 4
#define ROWS_PER_CHUNK (H_DIM / CHUNKS)
#define N_PLANES (B_DIM * C_DIM)      // 3072
#define N_PAIRS  (N_PLANES / 2)       // 1536

// ---------------- Kernel 1: adaptive avg pool (per-plane mean) ----------------
// (byte-identical to the verified 386.7us baseline version)
__global__ void pool_kernel(const float* __restrict__ x, float* __restrict__ pooled) {
    int plane = blockIdx.x;                       // b*96 + c, 3072 planes
    const float4* xp = (const float4*)(x + (size_t)plane * (H_DIM * W_DIM));
    float s = 0.f;
    for (int i = threadIdx.x; i < 4096; i += 256) {
        float4 v = xp[i];
        s += v.x + v.y + v.z + v.w;
    }
    for (int off = 32; off; off >>= 1) s += __shfl_down(s, off, 64);
    __shared__ float ls[4];
    int lane = threadIdx.x & 63, wv = threadIdx.x >> 6;
    if (lane == 0) ls[wv] = s;
    __syncthreads();
    if (threadIdx.x == 0) {
        float t = ls[0] + ls[1] + ls[2] + ls[3];
        pooled[plane] = t * (1.f / (H_DIM * W_DIM));
    }
}

// ---------------- Kernel 2: fused dynamic-weight MLP + per-sample depthwise 3x3 ----------------
// vs verified baseline:
//   * PLAIN float4 stores (was nontemporal).
//   * Prologue x-row loads issued BEFORE the MLP so load latency hides under h1.
//   * Bounds checks peeled out of the 30-iteration steady-state loop.
// CRITICAL (round-2 bug): shuffles are computed UNCONDITIONALLY and the edge
// select applied AFTER — ds_bpermute returns 0 for exec-masked source lanes,
// so a shuffle behind a lane-divergent ternary corrupts interior halos.
__global__ void __launch_bounds__(256) fused_dwconv_kernel(const float* __restrict__ x,
                                                           const float* __restrict__ pooled,
                                                           const float* __restrict__ w1,
                                                           const float* __restrict__ gamma,
                                                           const float* __restrict__ beta,
                                                           const float* __restrict__ rmean,
                                                           const float* __restrict__ rvar,
                                                           const float* __restrict__ w2,
                                                           const float* __restrict__ b2,
                                                           const float* __restrict__ bias,
                                                           float* __restrict__ out) {
    int tid = threadIdx.x;
    int plane0 = blockIdx.x * 2;            // even plane index
    int b = plane0 / C_DIM;
    int c0 = plane0 % C_DIM;                // channel of plane0; plane1 is c0+1

    // thread map: g = col group (float4), chunk = row chunk, p = plane-in-pair
    int g = tid & 31;
    int chunk = (tid >> 5) & 3;
    int p = tid >> 7;
    int plane = plane0 + p;
    int col = g << 2;
    int r0 = chunk * ROWS_PER_CHUNK;

    const float* xp = x + (size_t)plane * (H_DIM * W_DIM);
    float* op = out + (size_t)plane * (H_DIM * W_DIM);

    // ---- issue prologue row loads EARLY (latency hides under the MLP) ----
    float4 pvr; pvr.x = pvr.y = pvr.z = pvr.w = 0.f;
    if (r0 > 0) pvr = *(const float4*)(xp + (r0 - 1) * W_DIM + col);
    float4 cvr = *(const float4*)(xp + r0 * W_DIM + col);
    float4 nvr = *(const float4*)(xp + (r0 + 1) * W_DIM + col);   // r0+1 <= 97, always valid

    __shared__ float pl[C_DIM];
    __shared__ float h1[CR];
    __shared__ float wsm[2][10];            // 9 taps + bias per plane

    if (tid < C_DIM) pl[tid] = pooled[b * C_DIM + tid];
    __syncthreads();
    if (tid < CR) {
        float s = 0.f;
        const float* wr = w1 + tid * C_DIM;
        #pragma unroll 8
        for (int c = 0; c < C_DIM; c++) s += pl[c] * wr[c];
        s = (s - rmean[tid]) * rsqrtf(rvar[tid] + 1e-5f) * gamma[tid] + beta[tid];
        h1[tid] = 1.f / (1.f + expf(-s));
    }
    __syncthreads();
    if (tid < 20) {
        if (tid < 18) {
            int pp = tid / 9, k = tid % 9;
            int row = (c0 + pp) * 9 + k;    // wdyn flat index within batch
            float s = b2[row];
            const float* wr = w2 + row * CR;
            #pragma unroll
            for (int j = 0; j < CR; j++) s += h1[j] * wr[j];
            wsm[pp][k] = s;
        } else {
            wsm[tid - 18][9] = bias[c0 + (tid - 18)];
        }
    }
    __syncthreads();

    const float* wvp = wsm[p];
    float w00 = wvp[0], w01 = wvp[1], w02 = wvp[2];
    float w10 = wvp[3], w11 = wvp[4], w12 = wvp[5];
    float w20 = wvp[6], w21 = wvp[7], w22 = wvp[8];
    float bb = wvp[9];
    const bool leftEdge = (g == 0), rightEdge = (g == 31);

    // halos for the three prologue rows — shuffles UNCONDITIONAL, select after
    float4 pv = pvr, cv = cvr, nv = nvr;
    float t0 = __shfl_up(pvr.w, 1, 64);
    float t1 = __shfl_down(pvr.x, 1, 64);
    float t2 = __shfl_up(cvr.w, 1, 64);
    float t3 = __shfl_down(cvr.x, 1, 64);
    float t4 = __shfl_up(nvr.w, 1, 64);
    float t5 = __shfl_down(nvr.x, 1, 64);
    float plh = leftEdge ? 0.f : t0;
    float prh = rightEdge ? 0.f : t1;
    float clh = leftEdge ? 0.f : t2;
    float crh = rightEdge ? 0.f : t3;
    float nlh = leftEdge ? 0.f : t4;
    float nrh = rightEdge ? 0.f : t5;

#define COMPUTE_STORE(ROW)                                                   \
    {                                                                        \
        float4 o;                                                            \
        o.x = w00 * plh  + w01 * pv.x + w02 * pv.y                           \
            + w10 * clh  + w11 * cv.x + w12 * cv.y                           \
            + w20 * nlh  + w21 * nv.x + w22 * nv.y + bb;                     \
        o.y = w00 * pv.x + w01 * pv.y + w02 * pv.z                           \
            + w10 * cv.x + w11 * cv.y + w12 * cv.z                           \
            + w20 * nv.x + w21 * nv.y + w22 * nv.z + bb;                     \
        o.z = w00 * pv.y + w01 * pv.z + w02 * pv.w                           \
            + w10 * cv.y + w11 * cv.z + w12 * cv.w                           \
            + w20 * nv.y + w21 * nv.z + w22 * nv.w + bb;                     \
        o.w = w00 * pv.z + w01 * pv.w + w02 * prh                            \
            + w10 * cv.z + w11 * cv.w + w12 * crh                            \
            + w20 * nv.z + w21 * nv.w + w22 * nrh + bb;                      \
        *(float4*)(op + (ROW) * W_DIM + col) = o;                            \
    }

#define SHIFT_IN(V, L, R)                                                    \
    pv = cv; plh = clh; prh = crh;                                           \
    cv = nv; clh = nlh; crh = nrh;                                           \
    nv = (V); nlh = (L); nrh = (R);

    // steady state: rows r0 .. r0+29 — next-load row r0+i+2 <= r0+31 <= 127, no checks
    #pragma unroll 6
    for (int i = 0; i < 30; ++i) {
        int r = r0 + i;
        float4 v = *(const float4*)(xp + (r + 2) * W_DIM + col);
        float l = __shfl_up(v.w, 1, 64);
        float rr = __shfl_down(v.x, 1, 64);
        COMPUTE_STORE(r);
        SHIFT_IN(v, leftEdge ? 0.f : l, rightEdge ? 0.f : rr);
    }
    // peeled iter 30: load row r0+32 (invalid only for chunk 3)
    {
        int r = r0 + 30;
        float4 v; v.x = v.y = v.z = v.w = 0.f;
        if (r + 2 < H_DIM) v = *(const float4*)(xp + (r + 2) * W_DIM + col);
        float l = __shfl_up(v.w, 1, 64);
        float rr = __shfl_down(v.x, 1, 64);
        COMPUTE_STORE(r);
        SHIFT_IN(v, leftEdge ? 0.f : l, rightEdge ? 0.f : rr);
    }
    // peeled iter 31: no further load
    {
        int r = r0 + 31;
        COMPUTE_STORE(r);
    }
#undef COMPUTE_STORE
#undef SHIFT_IN
}

extern "C" void kernel_launch(void* const* d_in, const int* in_sizes, int n_in,
                              void* d_out, int out_size, void* d_ws, size_t ws_size,
                              hipStream_t stream) {
    const float* x     = (const float*)d_in[0];
    const float* w1    = (const float*)d_in[1];
    const float* gamma = (const float*)d_in[2];
    const float* beta  = (const float*)d_in[3];
    const float* rmean = (const float*)d_in[4];
    const float* rvar  = (const float*)d_in[5];
    const float* w2    = (const float*)d_in[6];
    const float* b2    = (const float*)d_in[7];
    const float* bias  = (const float*)d_in[8];
    float* out = (float*)d_out;

    float* pooled = (float*)d_ws;                           // 3072 floats

    pool_kernel<<<N_PLANES, 256, 0, stream>>>(x, pooled);
    fused_dwconv_kernel<<<N_PAIRS, 256, 0, stream>>>(
        x, pooled, w1, gamma, beta, rmean, rvar, w2, b2, bias, out);
}